// Round 4
// baseline (689.505 us; speedup 1.0000x reference)
//
#include <hip/hip_runtime.h>

#define HW 65536
#define WD 256
#define HD 256
#define CC 32

__device__ __forceinline__ float frelu(float v){ return v > 0.f ? v : 0.f; }

// ---------------- weight prep: transpose w1, fold+transpose w2/w3 ----------------
// CAT block order: 0=up 1=right 2=down 3=left 4=diagDR(zuoxia==zuoshang) 5=diagDL(youxia) 6=diagUR(youshang)
__global__ void prep_weights(const float* __restrict__ w1,
                             const float* __restrict__ w2,
                             const float* __restrict__ w3,
                             float* __restrict__ wt1,   // [64][32]
                             float* __restrict__ wf2,   // [224][32]
                             float* __restrict__ wf3) { // [224][32]
    int t = threadIdx.x;
    for (int idx = t; idx < 64 * 32; idx += 256) {
        int i = idx >> 5, o = idx & 31;
        wt1[idx] = w1[o * 64 + i];
    }
    for (int idx = t; idx < 224 * 32; idx += 256) {
        int j = idx >> 5, o = idx & 31;
        int blk = j >> 5, i = j & 31;
        int base = o * 256;
        float v2, v3;
        if (blk < 4)        { v2 = w2[base + blk*32 + i];                     v3 = w3[base + blk*32 + i]; }
        else if (blk == 4)  { v2 = w2[base + 128 + i] + w2[base + 192 + i];   v3 = w3[base + 128 + i] + w3[base + 192 + i]; }
        else if (blk == 5)  { v2 = w2[base + 160 + i];                        v3 = w3[base + 160 + i]; }
        else                { v2 = w2[base + 224 + i];                        v3 = w3[base + 224 + i]; }
        wf2[idx] = v2;
        wf3[idx] = v3;
    }
}

// ---------------- 1x1 conv, CIN split across 4 waves, LDS reduction ----------------
// block: 256 threads = 4 waves; 64 pixels/block; wave w handles CPW=CIN/4 channels.
// MODE 0: write 32ch; MODE 2: +bias, relu, dot(w_out) -> 1ch (fused conv3+conv_out)
template<int CIN, int MODE>
__global__ __launch_bounds__(256) void conv1x1_k(const float* __restrict__ in,
                                                 const float* __restrict__ wt,   // [CIN][32]
                                                 const float* __restrict__ bias, // [32]
                                                 const float* __restrict__ wo,   // [32] (MODE 2)
                                                 float* __restrict__ out) {
    constexpr int CPW = CIN / 4;
    constexpr int PF = 8;
    int t = threadIdx.x;
    int l = t & 63;          // pixel lane
    int w = t >> 6;          // wave id -> channel quarter
    int pix = blockIdx.x * 64 + l;
    int b = blockIdx.y;
    const float* ip = in + (size_t)b * CIN * HW + (size_t)(w * CPW) * HW + pix;
    const float* wp = wt + (w * CPW) * 32;

    float acc[32];
#pragma unroll
    for (int o = 0; o < 32; ++o) acc[o] = 0.f;

    float rbuf[PF];
#pragma unroll
    for (int j = 0; j < PF; ++j) rbuf[j] = ip[(size_t)j * HW];
#pragma unroll 1
    for (int i0 = 0; i0 < CPW - PF; i0 += PF) {
        const float* ipn = ip + (size_t)(i0 + PF) * HW;
        const float* wr0 = wp + i0 * 32;
#pragma unroll
        for (int j = 0; j < PF; ++j) {
            float v = rbuf[j];
            rbuf[j] = ipn[(size_t)j * HW];
#pragma unroll
            for (int o = 0; o < 32; ++o) acc[o] = fmaf(wr0[j * 32 + o], v, acc[o]);
        }
    }
    const float* wrL = wp + (CPW - PF) * 32;
#pragma unroll
    for (int j = 0; j < PF; ++j) {
        float v = rbuf[j];
#pragma unroll
        for (int o = 0; o < 32; ++o) acc[o] = fmaf(wrL[j * 32 + o], v, acc[o]);
    }

    // cross-wave reduction: waves 0..2 park partials in LDS, wave 3 combines
    __shared__ float red[3 * 64 * 33];   // [w][l][o], pad 33 -> bank (l+o)%32, 2-way free
    if (w < 3) {
#pragma unroll
        for (int o = 0; o < 32; ++o) red[(w * 64 + l) * 33 + o] = acc[o];
    }
    __syncthreads();
    if (w == 3) {
        float tot[32];
#pragma unroll
        for (int o = 0; o < 32; ++o) {
            tot[o] = acc[o] + bias[o]
                   + red[(0 * 64 + l) * 33 + o]
                   + red[(1 * 64 + l) * 33 + o]
                   + red[(2 * 64 + l) * 33 + o];
        }
        if (MODE == 2) {
            float m = 0.f;
#pragma unroll
            for (int o = 0; o < 32; ++o) m = fmaf(wo[o], frelu(tot[o]), m);
            out[(size_t)b * HW + pix] = m;
        } else {
            float* op = out + (size_t)b * 32 * HW + pix;
#pragma unroll
            for (int o = 0; o < 32; ++o) op[(size_t)o * HW] = tot[o];
        }
    }
}

// ---------------- merged scan kernel: all 7 directional scans in one launch ----------------
// grid (80, K), 256 threads.
//   bx 0..7  : row forward,  4 waves = channels bx*4 .. bx*4+3   (down, diagDR, diagDL)
//   bx 8..15 : row backward, 4 waves = channels (bx-8)*4 ..      (up, diagUR)
//   bx 16..79: col scans, (bx-16)>>5 = dir (0 right,1 left), (bx-16)&31 = channel
__global__ __launch_bounds__(256) void scan_all(const float* __restrict__ F,   // [Kb][32][HW]
                                                float* __restrict__ CAT,       // [Kb][7][32][HW]
                                                const float* __restrict__ irw) {
    int b = blockIdx.y;
    int bx = blockIdx.x;
    __shared__ float tile[256 * 33];
    const float wd = irw[2];

    if (bx < 16) {
        int dirb = bx >> 3;
        int wave = threadIdx.x >> 6;
        int t = threadIdx.x & 63;
        int c = (bx & 7) * 4 + wave;
        const float4* xr = (const float4*)(F + ((size_t)b * 32 + c) * HW);
        size_t catbase = (size_t)b * 7 * 32 * HW + (size_t)c * HW;
        constexpr int D = 8;
        float4 buf[D];

        if (dirb == 0) {   // forward: down(2), diagDR(4), diagDL(5)
            float4* o_dn = (float4*)(CAT + catbase + (size_t)2 * 32 * HW);
            float4* o_dr = (float4*)(CAT + catbase + (size_t)4 * 32 * HW);
            float4* o_dl = (float4*)(CAT + catbase + (size_t)5 * 32 * HW);
            float4 x0 = xr[t];
            o_dn[t] = x0; o_dr[t] = x0; o_dl[t] = x0;
            float dn0=x0.x, dn1=x0.y, dn2=x0.z, dn3=x0.w;
            float dr0=x0.x, dr1=x0.y, dr2=x0.z, dr3=x0.w;
            float dl0=x0.x, dl1=x0.y, dl2=x0.z, dl3=x0.w;
#pragma unroll
            for (int j = 0; j < D; ++j) buf[j] = xr[(1 + j) * 64 + t];
            for (int hb = 1; hb < HD; hb += D) {
#pragma unroll
                for (int j = 0; j < D; ++j) {
                    int h = hb + j;
                    if (h < HD) {
                        float4 xv = buf[j];
                        int hn = h + D; if (hn > HD - 1) hn = HD - 1;
                        buf[j] = xr[hn * 64 + t];
                        float nbL = __shfl_up(dr3, 1);
                        float nbR = __shfl_down(dl0, 1);
                        dn0 = frelu(fmaf(dn0, wd, xv.x));
                        dn1 = frelu(fmaf(dn1, wd, xv.y));
                        dn2 = frelu(fmaf(dn2, wd, xv.z));
                        dn3 = frelu(fmaf(dn3, wd, xv.w));
                        float a0 = (t == 0) ? xv.x : frelu(fmaf(nbL, wd, xv.x));
                        float a1 = frelu(fmaf(dr0, wd, xv.y));
                        float a2 = frelu(fmaf(dr1, wd, xv.z));
                        float a3 = frelu(fmaf(dr2, wd, xv.w));
                        dr0 = a0; dr1 = a1; dr2 = a2; dr3 = a3;
                        float e0 = frelu(fmaf(dl1, wd, xv.x));
                        float e1 = frelu(fmaf(dl2, wd, xv.y));
                        float e2 = frelu(fmaf(dl3, wd, xv.z));
                        float e3 = (t == 63) ? xv.w : frelu(fmaf(nbR, wd, xv.w));
                        dl0 = e0; dl1 = e1; dl2 = e2; dl3 = e3;
                        o_dn[h * 64 + t] = make_float4(dn0, dn1, dn2, dn3);
                        o_dr[h * 64 + t] = make_float4(a0, a1, a2, a3);
                        o_dl[h * 64 + t] = make_float4(e0, e1, e2, e3);
                    }
                }
            }
        } else {           // backward: up(0), diagUR(6)
            const float wu = irw[0];
            float4* o_up = (float4*)(CAT + catbase + (size_t)0 * 32 * HW);
            float4* o_ur = (float4*)(CAT + catbase + (size_t)6 * 32 * HW);
            float4 x0 = xr[(HD - 1) * 64 + t];
            o_up[(HD - 1) * 64 + t] = x0; o_ur[(HD - 1) * 64 + t] = x0;
            float up0=x0.x, up1=x0.y, up2=x0.z, up3=x0.w;
            float ur0=x0.x, ur1=x0.y, ur2=x0.z, ur3=x0.w;
#pragma unroll
            for (int j = 0; j < D; ++j) buf[j] = xr[(HD - 2 - j) * 64 + t];
            for (int hb = HD - 2; hb >= 0; hb -= D) {
#pragma unroll
                for (int j = 0; j < D; ++j) {
                    int h = hb - j;
                    if (h >= 0) {
                        float4 xv = buf[j];
                        int hn = h - D; if (hn < 0) hn = 0;
                        buf[j] = xr[hn * 64 + t];
                        float nbL = __shfl_up(ur3, 1);
                        up0 = frelu(fmaf(up0, wu, xv.x));
                        up1 = frelu(fmaf(up1, wu, xv.y));
                        up2 = frelu(fmaf(up2, wu, xv.z));
                        up3 = frelu(fmaf(up3, wu, xv.w));
                        float a0 = (t == 0) ? xv.x : frelu(fmaf(nbL, wd, xv.x));
                        float a1 = frelu(fmaf(ur0, wd, xv.y));
                        float a2 = frelu(fmaf(ur1, wd, xv.z));
                        float a3 = frelu(fmaf(ur2, wd, xv.w));
                        ur0 = a0; ur1 = a1; ur2 = a2; ur3 = a3;
                        o_up[h * 64 + t] = make_float4(up0, up1, up2, up3);
                        o_ur[h * 64 + t] = make_float4(a0, a1, a2, a3);
                    }
                }
            }
        }
    } else {
        // ---- col scans: right(1)/left(3), LDS-tiled, double-buffered ----
        int i = bx - 16;
        int dir = i >> 5;
        int c = i & 31;
        int t = threadIdx.x;
        const float wgt = (dir == 0) ? irw[1] : irw[3];
        const float* x = F + ((size_t)b * 32 + c) * HW;
        float* o = CAT + ((size_t)b * 7 + (dir == 0 ? 1 : 3)) * 32 * HW + (size_t)c * HW;
        int hh0 = t >> 5, ww = t & 31;
        float r[2][32];
        float carry = 0.f;
        {
            int wb0 = (dir == 0) ? 0 : 7 * 32;
#pragma unroll
            for (int k = 0; k < 32; ++k)
                r[0][k] = x[(k * 8 + hh0) * WD + wb0 + ww];
        }
#pragma unroll
        for (int tw = 0; tw < 8; ++tw) {
            int wbase = (dir == 0) ? tw * 32 : (7 - tw) * 32;
            const int cur = tw & 1, nxt = cur ^ 1;
            __syncthreads();
#pragma unroll
            for (int k = 0; k < 32; ++k)
                tile[(k * 8 + hh0) * 33 + ww] = r[cur][k];
            __syncthreads();
            if (tw < 7) {
                int wb2 = (dir == 0) ? (tw + 1) * 32 : (6 - tw) * 32;
#pragma unroll
                for (int k = 0; k < 32; ++k)
                    r[nxt][k] = x[(k * 8 + hh0) * WD + wb2 + ww];
            }
            if (dir == 0) {
#pragma unroll
                for (int j = 0; j < 32; ++j) {
                    float xv = tile[t * 33 + j];
                    carry = (wbase + j == 0) ? xv : frelu(fmaf(carry, wgt, xv));
                    tile[t * 33 + j] = carry;
                }
            } else {
#pragma unroll
                for (int j = 31; j >= 0; --j) {
                    float xv = tile[t * 33 + j];
                    carry = (wbase + j == WD - 1) ? xv : frelu(fmaf(carry, wgt, xv));
                    tile[t * 33 + j] = carry;
                }
            }
            __syncthreads();
#pragma unroll
            for (int k = 0; k < 32; ++k)
                o[(k * 8 + hh0) * WD + wbase + ww] = tile[(k * 8 + hh0) * 33 + ww];
        }
    }
}

extern "C" void kernel_launch(void* const* d_in, const int* in_sizes, int n_in,
                              void* d_out, int out_size, void* d_ws, size_t ws_size,
                              hipStream_t stream) {
    const float* x    = (const float*)d_in[0];
    const float* w1   = (const float*)d_in[1];
    const float* b1   = (const float*)d_in[2];
    const float* w2   = (const float*)d_in[3];
    const float* b2   = (const float*)d_in[4];
    const float* w3   = (const float*)d_in[5];
    const float* b3   = (const float*)d_in[6];
    const float* wout = (const float*)d_in[7];
    const float* ir1  = (const float*)d_in[8];
    const float* ir2  = (const float*)d_in[9];

    const size_t fbytes = (size_t)CC * HW * sizeof(float);  // 8 MB per batch-image
    const size_t wbytes = (64 * 32 + 2 * 224 * 32) * sizeof(float);

    // need K*(1 F + 7 CAT)*8MB + weights
    int K = 4;
    while (K > 1 && ((size_t)K * 8 * fbytes + wbytes) > ws_size) K >>= 1;

    char* ws = (char*)d_ws;
    float* F   = (float*)ws;  ws += (size_t)K * fbytes;
    float* CAT = (float*)ws;  ws += (size_t)K * 7 * fbytes;
    float* WT1 = (float*)ws;  ws += 64 * 32 * sizeof(float);
    float* WF2 = (float*)ws;  ws += 224 * 32 * sizeof(float);
    float* WF3 = (float*)ws;

    prep_weights<<<1, 256, 0, stream>>>(w1, w2, w3, WT1, WF2, WF3);

    for (int b0 = 0; b0 < 4; b0 += K) {
        conv1x1_k<64, 0><<<dim3(HW / 64, K), 256, 0, stream>>>(
            x + (size_t)b0 * 64 * HW, WT1, b1, nullptr, F);
        scan_all<<<dim3(80, K), 256, 0, stream>>>(F, CAT, ir1);
        conv1x1_k<224, 0><<<dim3(HW / 64, K), 256, 0, stream>>>(CAT, WF2, b2, nullptr, F);
        scan_all<<<dim3(80, K), 256, 0, stream>>>(F, CAT, ir2);
        conv1x1_k<224, 2><<<dim3(HW / 64, K), 256, 0, stream>>>(
            CAT, WF3, b3, wout, (float*)d_out + (size_t)b0 * HW);
    }
}

// Round 6
// 229.850 us; speedup vs baseline: 2.9998x; 2.9998x over previous
//
#include <hip/hip_runtime.h>
#include <hip/hip_bf16.h>

#define HW 65536
#define WD 256
#define HD 256

typedef unsigned short u16;
typedef __attribute__((ext_vector_type(8))) short short8;
typedef __attribute__((ext_vector_type(4))) float f32x4;

__device__ __forceinline__ float frelu(float v){ return v > 0.f ? v : 0.f; }
__device__ __forceinline__ float b2f(u16 u){ unsigned v = (unsigned)u << 16; float f; __builtin_memcpy(&f, &v, 4); return f; }
__device__ __forceinline__ u16 f2b(float f){ __hip_bfloat16 h = __float2bfloat16(f); u16 u; __builtin_memcpy(&u, &h, 2); return u; }
__device__ __forceinline__ ushort4 pack4(float a, float b, float c, float d){
    ushort4 r; r.x = f2b(a); r.y = f2b(b); r.z = f2b(c); r.w = f2b(d); return r;
}

// CAT_T layout: [px>>4][224][16] bf16 panels. folded channel blocks:
// 0=up 1=right 2=down 3=left 4=diagDR(zuoxia+zuoshang) 5=diagDL 6=diagUR
// ---------------- weight prep ----------------
__global__ void prep_weights(const float* __restrict__ w1,
                             const float* __restrict__ w2,
                             const float* __restrict__ w3,
                             float* __restrict__ wt1,   // [64][32] fp32
                             u16* __restrict__ wp2,     // [7][2][64][8] bf16 A-frags
                             u16* __restrict__ wp3) {
    int t = threadIdx.x;
    for (int idx = t; idx < 64 * 32; idx += 256) {
        int i = idx >> 5, o = idx & 31;
        wt1[idx] = w1[o * 64 + i];
    }
    // A-frag pack: lane l holds W[row=l&15 (+16*m)][k=s*32+(l>>4)*8+j]
    for (int idx = t; idx < 7 * 2 * 64 * 8; idx += 256) {
        int j = idx & 7, l = (idx >> 3) & 63, m = (idx >> 9) & 1, s = idx >> 10;
        int o = m * 16 + (l & 15);
        int k = s * 32 + ((l >> 4) * 8) + j;   // folded channel in [0,224)
        int blk = k >> 5, i = k & 31, base = o * 256;
        float v2, v3;
        if (blk < 4)        { v2 = w2[base + blk*32 + i];                   v3 = w3[base + blk*32 + i]; }
        else if (blk == 4)  { v2 = w2[base + 128 + i] + w2[base + 192 + i]; v3 = w3[base + 128 + i] + w3[base + 192 + i]; }
        else if (blk == 5)  { v2 = w2[base + 160 + i];                      v3 = w3[base + 160 + i]; }
        else                { v2 = w2[base + 224 + i];                      v3 = w3[base + 224 + i]; }
        wp2[idx] = f2b(v2);
        wp3[idx] = f2b(v3);
    }
}

// ---------------- conv1: 64ch fp32 -> 32ch bf16, vector FMA ----------------
__global__ __launch_bounds__(256) void conv1_k(const float* __restrict__ in,   // [kk][64][HW]
                                               const float* __restrict__ wt,   // [64][32]
                                               const float* __restrict__ bias,
                                               u16* __restrict__ out) {        // [kk][32][HW]
    int p = blockIdx.x * 256 + threadIdx.x;
    int b = blockIdx.y;
    const float* ip = in + (size_t)b * 64 * HW + p;
    float acc[32];
#pragma unroll
    for (int o = 0; o < 32; ++o) acc[o] = bias[o];
    constexpr int PF = 16;
    float rbuf[PF];
#pragma unroll
    for (int j = 0; j < PF; ++j) rbuf[j] = ip[(size_t)j * HW];
#pragma unroll 1
    for (int i0 = 0; i0 < 64 - PF; i0 += PF) {
        const float* ipn = ip + (size_t)(i0 + PF) * HW;
        const float* wr0 = wt + i0 * 32;
#pragma unroll
        for (int j = 0; j < PF; ++j) {
            float v = rbuf[j];
            rbuf[j] = ipn[(size_t)j * HW];
#pragma unroll
            for (int o = 0; o < 32; ++o) acc[o] = fmaf(wr0[j * 32 + o], v, acc[o]);
        }
    }
    const float* wrL = wt + (64 - PF) * 32;
#pragma unroll
    for (int j = 0; j < PF; ++j) {
        float v = rbuf[j];
#pragma unroll
        for (int o = 0; o < 32; ++o) acc[o] = fmaf(wrL[j * 32 + o], v, acc[o]);
    }
    u16* op = out + (size_t)b * 32 * HW + p;
#pragma unroll
    for (int o = 0; o < 32; ++o) op[(size_t)o * HW] = f2b(acc[o]);
}

// ---------------- merged scans: F bf16 -> CAT_T bf16 ----------------
// grid (80, kk), 256 thr. bx 0..7 row-fwd (4 waves=4 ch), 8..15 row-bwd, 16..79 col scans.
__global__ __launch_bounds__(256) void scan_all(const u16* __restrict__ F,    // [kk][32][HW]
                                                u16* __restrict__ CATT,       // [kk][HW/16][224][16]
                                                const float* __restrict__ irw) {
    int b = blockIdx.y;
    int bx = blockIdx.x;
    __shared__ float stile[256 * 33];
    const float wd = irw[2];
    u16* catt = CATT + (size_t)b * HW * 224;

    if (bx < 16) {
        int dirb = bx >> 3;
        int wave = threadIdx.x >> 6;
        int t = threadIdx.x & 63;
        int c = (bx & 7) * 4 + wave;
        const ushort4* xr = (const ushort4*)(F + ((size_t)b * 32 + c) * HW);
        // cat elem offset for (h, lane t, channel-block blk): px = 4t of row h
        int lo = (t >> 2) * 3584 + (4 * t & 15);
        constexpr int D = 8;
        ushort4 buf[D];

        if (dirb == 0) {   // forward: down(2), diagDR(4), diagDL(5)
            size_t o_dn = (size_t)(2 * 32 + c) * 16 + lo;
            size_t o_dr = (size_t)(4 * 32 + c) * 16 + lo;
            size_t o_dl = (size_t)(5 * 32 + c) * 16 + lo;
            ushort4 xu = xr[t];
            float x0 = b2f(xu.x), x1 = b2f(xu.y), x2 = b2f(xu.z), x3 = b2f(xu.w);
            *(ushort4*)(catt + o_dn) = xu;
            *(ushort4*)(catt + o_dr) = xu;
            *(ushort4*)(catt + o_dl) = xu;
            float dn0=x0, dn1=x1, dn2=x2, dn3=x3;
            float dr0=x0, dr1=x1, dr2=x2, dr3=x3;
            float dl0=x0, dl1=x1, dl2=x2, dl3=x3;
#pragma unroll
            for (int j = 0; j < D; ++j) buf[j] = xr[(1 + j) * 64 + t];
            for (int hb = 1; hb < HD; hb += D) {
#pragma unroll
                for (int j = 0; j < D; ++j) {
                    int h = hb + j;
                    if (h < HD) {
                        ushort4 xv = buf[j];
                        int hn = h + D; if (hn > HD - 1) hn = HD - 1;
                        buf[j] = xr[hn * 64 + t];
                        float v0 = b2f(xv.x), v1 = b2f(xv.y), v2 = b2f(xv.z), v3 = b2f(xv.w);
                        float nbL = __shfl_up(dr3, 1);
                        float nbR = __shfl_down(dl0, 1);
                        dn0 = frelu(fmaf(dn0, wd, v0));
                        dn1 = frelu(fmaf(dn1, wd, v1));
                        dn2 = frelu(fmaf(dn2, wd, v2));
                        dn3 = frelu(fmaf(dn3, wd, v3));
                        float a0 = (t == 0) ? v0 : frelu(fmaf(nbL, wd, v0));
                        float a1 = frelu(fmaf(dr0, wd, v1));
                        float a2 = frelu(fmaf(dr1, wd, v2));
                        float a3 = frelu(fmaf(dr2, wd, v3));
                        dr0 = a0; dr1 = a1; dr2 = a2; dr3 = a3;
                        float e0 = frelu(fmaf(dl1, wd, v0));
                        float e1 = frelu(fmaf(dl2, wd, v1));
                        float e2 = frelu(fmaf(dl3, wd, v2));
                        float e3 = (t == 63) ? v3 : frelu(fmaf(nbR, wd, v3));
                        dl0 = e0; dl1 = e1; dl2 = e2; dl3 = e3;
                        size_t hb16 = (size_t)(h * 16) * 3584;
                        *(ushort4*)(catt + hb16 + o_dn) = pack4(dn0, dn1, dn2, dn3);
                        *(ushort4*)(catt + hb16 + o_dr) = pack4(a0, a1, a2, a3);
                        *(ushort4*)(catt + hb16 + o_dl) = pack4(e0, e1, e2, e3);
                    }
                }
            }
        } else {           // backward: up(0), diagUR(6)
            const float wu = irw[0];
            size_t o_up = (size_t)(0 * 32 + c) * 16 + lo;
            size_t o_ur = (size_t)(6 * 32 + c) * 16 + lo;
            ushort4 xu = xr[(HD - 1) * 64 + t];
            float x0 = b2f(xu.x), x1 = b2f(xu.y), x2 = b2f(xu.z), x3 = b2f(xu.w);
            size_t hbL = (size_t)((HD - 1) * 16) * 3584;
            *(ushort4*)(catt + hbL + o_up) = xu;
            *(ushort4*)(catt + hbL + o_ur) = xu;
            float up0=x0, up1=x1, up2=x2, up3=x3;
            float ur0=x0, ur1=x1, ur2=x2, ur3=x3;
#pragma unroll
            for (int j = 0; j < D; ++j) buf[j] = xr[(HD - 2 - j) * 64 + t];
            for (int hb = HD - 2; hb >= 0; hb -= D) {
#pragma unroll
                for (int j = 0; j < D; ++j) {
                    int h = hb - j;
                    if (h >= 0) {
                        ushort4 xv = buf[j];
                        int hn = h - D; if (hn < 0) hn = 0;
                        buf[j] = xr[hn * 64 + t];
                        float v0 = b2f(xv.x), v1 = b2f(xv.y), v2 = b2f(xv.z), v3 = b2f(xv.w);
                        float nbL = __shfl_up(ur3, 1);
                        up0 = frelu(fmaf(up0, wu, v0));
                        up1 = frelu(fmaf(up1, wu, v1));
                        up2 = frelu(fmaf(up2, wu, v2));
                        up3 = frelu(fmaf(up3, wu, v3));
                        float a0 = (t == 0) ? v0 : frelu(fmaf(nbL, wd, v0));
                        float a1 = frelu(fmaf(ur0, wd, v1));
                        float a2 = frelu(fmaf(ur1, wd, v2));
                        float a3 = frelu(fmaf(ur2, wd, v3));
                        ur0 = a0; ur1 = a1; ur2 = a2; ur3 = a3;
                        size_t hb16 = (size_t)(h * 16) * 3584;
                        *(ushort4*)(catt + hb16 + o_up) = pack4(up0, up1, up2, up3);
                        *(ushort4*)(catt + hb16 + o_ur) = pack4(a0, a1, a2, a3);
                    }
                }
            }
        }
    } else {
        // col scans: right(1)/left(3), LDS-tiled, double-buffered
        int i = bx - 16;
        int dir = i >> 5;
        int c = i & 31;
        int t = threadIdx.x;
        const float wgt = (dir == 0) ? irw[1] : irw[3];
        const u16* x = F + ((size_t)b * 32 + c) * HW;
        int chg = (dir == 0 ? 1 : 3) * 32 + c;
        int hh0 = t >> 5, ww = t & 31;
        float r[2][32];
        float carry = 0.f;
        {
            int wb0 = (dir == 0) ? 0 : 7 * 32;
#pragma unroll
            for (int k = 0; k < 32; ++k)
                r[0][k] = b2f(x[(k * 8 + hh0) * WD + wb0 + ww]);
        }
#pragma unroll
        for (int tw = 0; tw < 8; ++tw) {
            int wbase = (dir == 0) ? tw * 32 : (7 - tw) * 32;
            const int cur = tw & 1, nxt = cur ^ 1;
            __syncthreads();
#pragma unroll
            for (int k = 0; k < 32; ++k)
                stile[(k * 8 + hh0) * 33 + ww] = r[cur][k];
            __syncthreads();
            if (tw < 7) {
                int wb2 = (dir == 0) ? (tw + 1) * 32 : (6 - tw) * 32;
#pragma unroll
                for (int k = 0; k < 32; ++k)
                    r[nxt][k] = b2f(x[(k * 8 + hh0) * WD + wb2 + ww]);
            }
            if (dir == 0) {
#pragma unroll
                for (int j = 0; j < 32; ++j) {
                    float xv = stile[t * 33 + j];
                    carry = (wbase + j == 0) ? xv : frelu(fmaf(carry, wgt, xv));
                    stile[t * 33 + j] = carry;
                }
            } else {
#pragma unroll
                for (int j = 31; j >= 0; --j) {
                    float xv = stile[t * 33 + j];
                    carry = (wbase + j == WD - 1) ? xv : frelu(fmaf(carry, wgt, xv));
                    stile[t * 33 + j] = carry;
                }
            }
            __syncthreads();
#pragma unroll
            for (int k = 0; k < 32; ++k) {
                int row = k * 8 + hh0;
                int col = wbase + ww;
                float val = stile[row * 33 + ww];
                size_t off = (size_t)(row * 16 + (col >> 4)) * 3584 + (size_t)chg * 16 + (col & 15);
                catt[off] = f2b(val);
            }
        }
    }
}

// ---------------- MFMA conv: OUT[32][HW] = W[32][224] x CAT_T ----------------
// block 256 thr = 4 waves; wave owns 2 px-tiles (32 px); 7 K-slabs of 32.
// B-fragments loaded DIRECTLY from global (8 x u16 per slab-tile per lane),
// packed in-register; ping-pong double buffer, fully static indexing.
// MODE 0: +bias -> F bf16 ; MODE 2: +bias, relu, dot(wo) -> fp32 out
template<int MODE>
__global__ __launch_bounds__(256) void conv_mfma(const u16* __restrict__ CATT, // [kk][HW/16][224][16]
                                                 const u16* __restrict__ WP,   // [7][2][64][8]
                                                 const float* __restrict__ bias,
                                                 const float* __restrict__ wo,
                                                 u16* __restrict__ Fout,
                                                 float* __restrict__ out) {
    int t = threadIdx.x & 63;
    int w = threadIdx.x >> 6;
    int b = blockIdx.y;
    int tile0 = blockIdx.x * 8 + w * 2;
    const u16* catb = CATT + (size_t)b * HW * 224;
    const u16* p0 = catb + (size_t)tile0 * 3584;
    const u16* p1 = p0 + 3584;
    // lane's B-column: col=t&15, row-base q*8 (q=t>>4); u16 offset q*128 + col
    int lq = ((t >> 4) * 128) + (t & 15);

    // A-fragment preload (14 x 16B, L2-hot)
    const short8* ap = (const short8*)WP;
    short8 A[7][2];
#pragma unroll
    for (int s = 0; s < 7; ++s) {
        A[s][0] = ap[(s * 2 + 0) * 64 + t];
        A[s][1] = ap[(s * 2 + 1) * 64 + t];
    }

    f32x4 acc[2][2];
#pragma unroll
    for (int tl = 0; tl < 2; ++tl)
#pragma unroll
        for (int m = 0; m < 2; ++m) acc[tl][m] = (f32x4){0.f, 0.f, 0.f, 0.f};

    u16 rb[2][2][8];   // [phase][tile][j] — all indices compile-time after unroll
#pragma unroll
    for (int j = 0; j < 8; ++j) {
        rb[0][0][j] = p0[lq + j * 16];
        rb[0][1][j] = p1[lq + j * 16];
    }
#pragma unroll
    for (int s = 0; s < 7; ++s) {
        const int cur = s & 1, nxt = cur ^ 1;
        if (s < 6) {
#pragma unroll
            for (int j = 0; j < 8; ++j) {
                rb[nxt][0][j] = p0[(s + 1) * 512 + lq + j * 16];
                rb[nxt][1][j] = p1[(s + 1) * 512 + lq + j * 16];
            }
        }
        short8 B0, B1;
#pragma unroll
        for (int j = 0; j < 8; ++j) {
            B0[j] = (short)rb[cur][0][j];
            B1[j] = (short)rb[cur][1][j];
        }
        acc[0][0] = __builtin_amdgcn_mfma_f32_16x16x32_bf16(A[s][0], B0, acc[0][0], 0, 0, 0);
        acc[0][1] = __builtin_amdgcn_mfma_f32_16x16x32_bf16(A[s][1], B0, acc[0][1], 0, 0, 0);
        acc[1][0] = __builtin_amdgcn_mfma_f32_16x16x32_bf16(A[s][0], B1, acc[1][0], 0, 0, 0);
        acc[1][1] = __builtin_amdgcn_mfma_f32_16x16x32_bf16(A[s][1], B1, acc[1][1], 0, 0, 0);
    }

    // C/D: lane t holds col px=(t&15), rows ch=(t>>4)*4+r (+16*m)
    if (MODE == 0) {
        u16* fb = Fout + (size_t)b * 32 * HW;
#pragma unroll
        for (int tl = 0; tl < 2; ++tl) {
            int px = (tile0 + tl) * 16 + (t & 15);
#pragma unroll
            for (int m = 0; m < 2; ++m)
#pragma unroll
                for (int r = 0; r < 4; ++r) {
                    int ch = m * 16 + (t >> 4) * 4 + r;
                    fb[(size_t)ch * HW + px] = f2b(acc[tl][m][r] + bias[ch]);
                }
        }
    } else {
        float mres0 = 0.f, mres1 = 0.f;
#pragma unroll
        for (int m = 0; m < 2; ++m)
#pragma unroll
            for (int r = 0; r < 4; ++r) {
                int ch = m * 16 + (t >> 4) * 4 + r;
                float wv = wo[ch], bv = bias[ch];
                mres0 = fmaf(wv, frelu(acc[0][m][r] + bv), mres0);
                mres1 = fmaf(wv, frelu(acc[1][m][r] + bv), mres1);
            }
        mres0 += __shfl_xor(mres0, 16); mres0 += __shfl_xor(mres0, 32);
        mres1 += __shfl_xor(mres1, 16); mres1 += __shfl_xor(mres1, 32);
        if (t < 16) {
            out[(size_t)b * HW + (tile0 + 0) * 16 + t] = mres0;
            out[(size_t)b * HW + (tile0 + 1) * 16 + t] = mres1;
        }
    }
}

extern "C" void kernel_launch(void* const* d_in, const int* in_sizes, int n_in,
                              void* d_out, int out_size, void* d_ws, size_t ws_size,
                              hipStream_t stream) {
    const float* x    = (const float*)d_in[0];
    const float* w1   = (const float*)d_in[1];
    const float* b1   = (const float*)d_in[2];
    const float* w2   = (const float*)d_in[3];
    const float* b2   = (const float*)d_in[4];
    const float* w3   = (const float*)d_in[5];
    const float* b3   = (const float*)d_in[6];
    const float* wout = (const float*)d_in[7];
    const float* ir1  = (const float*)d_in[8];
    const float* ir2  = (const float*)d_in[9];

    const size_t fb   = (size_t)32 * HW * 2;        // F bf16: 4 MB/img
    const size_t cb   = (size_t)HW * 224 * 2;       // CAT_T bf16: 29.36 MB/img
    const size_t wext = 64 * 32 * 4 + 2 * 7168 * 2;

    int K = 4;
    while (K > 1 && (size_t)K * (fb + cb) + wext > ws_size) K--;

    char* ws = (char*)d_ws;
    u16*   F    = (u16*)ws;   ws += (size_t)K * fb;
    u16*   CATT = (u16*)ws;   ws += (size_t)K * cb;
    float* WT1  = (float*)ws; ws += 64 * 32 * 4;
    u16*   WP2  = (u16*)ws;   ws += 7168 * 2;
    u16*   WP3  = (u16*)ws;

    prep_weights<<<1, 256, 0, stream>>>(w1, w2, w3, WT1, WP2, WP3);

    for (int b0 = 0; b0 < 4; b0 += K) {
        int kk = (4 - b0 < K) ? (4 - b0) : K;
        conv1_k<<<dim3(HW / 256, kk), 256, 0, stream>>>(
            x + (size_t)b0 * 64 * HW, WT1, b1, F);
        scan_all<<<dim3(80, kk), 256, 0, stream>>>(F, CATT, ir1);
        conv_mfma<0><<<dim3(HW / 128, kk), 256, 0, stream>>>(
            CATT, WP2, b2, nullptr, F, nullptr);
        scan_all<<<dim3(80, kk), 256, 0, stream>>>(F, CATT, ir2);
        conv_mfma<2><<<dim3(HW / 128, kk), 256, 0, stream>>>(
            CATT, WP3, b3, wout, nullptr, (float*)d_out + (size_t)b0 * HW);
    }
}

// Round 7
// 186.481 us; speedup vs baseline: 3.6974x; 1.2326x over previous
//
#include <hip/hip_runtime.h>
#include <hip/hip_bf16.h>

#define HW 65536
#define WD 256
#define HD 256

typedef unsigned short u16;
typedef __attribute__((ext_vector_type(8))) short short8;
typedef __attribute__((ext_vector_type(4))) float f32x4;

__device__ __forceinline__ float frelu(float v){ return v > 0.f ? v : 0.f; }
__device__ __forceinline__ float b2f(u16 u){ unsigned v = (unsigned)u << 16; float f; __builtin_memcpy(&f, &v, 4); return f; }
__device__ __forceinline__ u16 f2b(float f){ __hip_bfloat16 h = __float2bfloat16(f); u16 u; __builtin_memcpy(&u, &h, 2); return u; }
__device__ __forceinline__ ushort4 pack4(float a, float b, float c, float d){
    ushort4 r; r.x = f2b(a); r.y = f2b(b); r.z = f2b(c); r.w = f2b(d); return r;
}

// CAT layout: LINEAR [224][HW] bf16 per image. folded channel blocks (x32 ch):
// 0=up 1=right 2=down 3=left 4=diagDR(zuoxia+zuoshang) 5=diagDL 6=diagUR
// ---------------- weight prep ----------------
__global__ void prep_weights(const float* __restrict__ w1,
                             const float* __restrict__ w2,
                             const float* __restrict__ w3,
                             float* __restrict__ wt1,   // [64][32] fp32
                             u16* __restrict__ wp2,     // [7][2][64][8] bf16 A-frags
                             u16* __restrict__ wp3) {
    int t = threadIdx.x;
    for (int idx = t; idx < 64 * 32; idx += 256) {
        int i = idx >> 5, o = idx & 31;
        wt1[idx] = w1[o * 64 + i];
    }
    // A-frag pack: lane l holds W[row=l&15 (+16*m)][k=s*32+(l>>4)*8+j]
    for (int idx = t; idx < 7 * 2 * 64 * 8; idx += 256) {
        int j = idx & 7, l = (idx >> 3) & 63, m = (idx >> 9) & 1, s = idx >> 10;
        int o = m * 16 + (l & 15);
        int k = s * 32 + ((l >> 4) * 8) + j;   // folded channel in [0,224)
        int blk = k >> 5, i = k & 31, base = o * 256;
        float v2, v3;
        if (blk < 4)        { v2 = w2[base + blk*32 + i];                   v3 = w3[base + blk*32 + i]; }
        else if (blk == 4)  { v2 = w2[base + 128 + i] + w2[base + 192 + i]; v3 = w3[base + 128 + i] + w3[base + 192 + i]; }
        else if (blk == 5)  { v2 = w2[base + 160 + i];                      v3 = w3[base + 160 + i]; }
        else                { v2 = w2[base + 224 + i];                      v3 = w3[base + 224 + i]; }
        wp2[idx] = f2b(v2);
        wp3[idx] = f2b(v3);
    }
}

// ---------------- conv1: 64ch fp32 -> 32ch bf16, vector FMA ----------------
__global__ __launch_bounds__(256) void conv1_k(const float* __restrict__ in,   // [kk][64][HW]
                                               const float* __restrict__ wt,   // [64][32]
                                               const float* __restrict__ bias,
                                               u16* __restrict__ out) {        // [kk][32][HW]
    int p = blockIdx.x * 256 + threadIdx.x;
    int b = blockIdx.y;
    const float* ip = in + (size_t)b * 64 * HW + p;
    float acc[32];
#pragma unroll
    for (int o = 0; o < 32; ++o) acc[o] = bias[o];
    constexpr int PF = 16;
    float rbuf[PF];
#pragma unroll
    for (int j = 0; j < PF; ++j) rbuf[j] = ip[(size_t)j * HW];
#pragma unroll 1
    for (int i0 = 0; i0 < 64 - PF; i0 += PF) {
        const float* ipn = ip + (size_t)(i0 + PF) * HW;
        const float* wr0 = wt + i0 * 32;
#pragma unroll
        for (int j = 0; j < PF; ++j) {
            float v = rbuf[j];
            rbuf[j] = ipn[(size_t)j * HW];
#pragma unroll
            for (int o = 0; o < 32; ++o) acc[o] = fmaf(wr0[j * 32 + o], v, acc[o]);
        }
    }
    const float* wrL = wt + (64 - PF) * 32;
#pragma unroll
    for (int j = 0; j < PF; ++j) {
        float v = rbuf[j];
#pragma unroll
        for (int o = 0; o < 32; ++o) acc[o] = fmaf(wrL[j * 32 + o], v, acc[o]);
    }
    u16* op = out + (size_t)b * 32 * HW + p;
#pragma unroll
    for (int o = 0; o < 32; ++o) op[(size_t)o * HW] = f2b(acc[o]);
}

// ---------------- merged scans: F bf16 -> CAT bf16 (linear) ----------------
// grid (80, kk), 256 thr. bx 0..7 row-fwd (4 waves=4 ch), 8..15 row-bwd, 16..79 col scans.
__global__ __launch_bounds__(256) void scan_all(const u16* __restrict__ F,    // [kk][32][HW]
                                                u16* __restrict__ CAT,        // [kk][224][HW]
                                                const float* __restrict__ irw) {
    int b = blockIdx.y;
    int bx = blockIdx.x;
    __shared__ float stile[256 * 33];
    const float wd = irw[2];
    u16* catt = CAT + (size_t)b * 224 * HW;

    if (bx < 16) {
        int dirb = bx >> 3;
        int wave = threadIdx.x >> 6;
        int t = threadIdx.x & 63;
        int c = (bx & 7) * 4 + wave;
        const ushort4* xr = (const ushort4*)(F + ((size_t)b * 32 + c) * HW);
        constexpr int D = 8;
        ushort4 buf[D];

        if (dirb == 0) {   // forward: down(2), diagDR(4), diagDL(5)
            ushort4* o_dn = (ushort4*)(catt + (size_t)(2 * 32 + c) * HW);
            ushort4* o_dr = (ushort4*)(catt + (size_t)(4 * 32 + c) * HW);
            ushort4* o_dl = (ushort4*)(catt + (size_t)(5 * 32 + c) * HW);
            ushort4 xu = xr[t];
            float x0 = b2f(xu.x), x1 = b2f(xu.y), x2 = b2f(xu.z), x3 = b2f(xu.w);
            o_dn[t] = xu; o_dr[t] = xu; o_dl[t] = xu;
            float dn0=x0, dn1=x1, dn2=x2, dn3=x3;
            float dr0=x0, dr1=x1, dr2=x2, dr3=x3;
            float dl0=x0, dl1=x1, dl2=x2, dl3=x3;
#pragma unroll
            for (int j = 0; j < D; ++j) buf[j] = xr[(1 + j) * 64 + t];
            for (int hb = 1; hb < HD; hb += D) {
#pragma unroll
                for (int j = 0; j < D; ++j) {
                    int h = hb + j;
                    if (h < HD) {
                        ushort4 xv = buf[j];
                        int hn = h + D; if (hn > HD - 1) hn = HD - 1;
                        buf[j] = xr[hn * 64 + t];
                        float v0 = b2f(xv.x), v1 = b2f(xv.y), v2 = b2f(xv.z), v3 = b2f(xv.w);
                        float nbL = __shfl_up(dr3, 1);
                        float nbR = __shfl_down(dl0, 1);
                        dn0 = frelu(fmaf(dn0, wd, v0));
                        dn1 = frelu(fmaf(dn1, wd, v1));
                        dn2 = frelu(fmaf(dn2, wd, v2));
                        dn3 = frelu(fmaf(dn3, wd, v3));
                        float a0 = (t == 0) ? v0 : frelu(fmaf(nbL, wd, v0));
                        float a1 = frelu(fmaf(dr0, wd, v1));
                        float a2 = frelu(fmaf(dr1, wd, v2));
                        float a3 = frelu(fmaf(dr2, wd, v3));
                        dr0 = a0; dr1 = a1; dr2 = a2; dr3 = a3;
                        float e0 = frelu(fmaf(dl1, wd, v0));
                        float e1 = frelu(fmaf(dl2, wd, v1));
                        float e2 = frelu(fmaf(dl3, wd, v2));
                        float e3 = (t == 63) ? v3 : frelu(fmaf(nbR, wd, v3));
                        dl0 = e0; dl1 = e1; dl2 = e2; dl3 = e3;
                        o_dn[h * 64 + t] = pack4(dn0, dn1, dn2, dn3);
                        o_dr[h * 64 + t] = pack4(a0, a1, a2, a3);
                        o_dl[h * 64 + t] = pack4(e0, e1, e2, e3);
                    }
                }
            }
        } else {           // backward: up(0), diagUR(6)
            const float wu = irw[0];
            ushort4* o_up = (ushort4*)(catt + (size_t)(0 * 32 + c) * HW);
            ushort4* o_ur = (ushort4*)(catt + (size_t)(6 * 32 + c) * HW);
            ushort4 xu = xr[(HD - 1) * 64 + t];
            float x0 = b2f(xu.x), x1 = b2f(xu.y), x2 = b2f(xu.z), x3 = b2f(xu.w);
            o_up[(HD - 1) * 64 + t] = xu; o_ur[(HD - 1) * 64 + t] = xu;
            float up0=x0, up1=x1, up2=x2, up3=x3;
            float ur0=x0, ur1=x1, ur2=x2, ur3=x3;
#pragma unroll
            for (int j = 0; j < D; ++j) buf[j] = xr[(HD - 2 - j) * 64 + t];
            for (int hb = HD - 2; hb >= 0; hb -= D) {
#pragma unroll
                for (int j = 0; j < D; ++j) {
                    int h = hb - j;
                    if (h >= 0) {
                        ushort4 xv = buf[j];
                        int hn = h - D; if (hn < 0) hn = 0;
                        buf[j] = xr[hn * 64 + t];
                        float v0 = b2f(xv.x), v1 = b2f(xv.y), v2 = b2f(xv.z), v3 = b2f(xv.w);
                        float nbL = __shfl_up(ur3, 1);
                        up0 = frelu(fmaf(up0, wu, v0));
                        up1 = frelu(fmaf(up1, wu, v1));
                        up2 = frelu(fmaf(up2, wu, v2));
                        up3 = frelu(fmaf(up3, wu, v3));
                        float a0 = (t == 0) ? v0 : frelu(fmaf(nbL, wd, v0));
                        float a1 = frelu(fmaf(ur0, wd, v1));
                        float a2 = frelu(fmaf(ur1, wd, v2));
                        float a3 = frelu(fmaf(ur2, wd, v3));
                        ur0 = a0; ur1 = a1; ur2 = a2; ur3 = a3;
                        o_up[h * 64 + t] = pack4(up0, up1, up2, up3);
                        o_ur[h * 64 + t] = pack4(a0, a1, a2, a3);
                    }
                }
            }
        }
    } else {
        // col scans: right(1)/left(3), LDS-tiled, double-buffered, ushort4 I/O
        int i = bx - 16;
        int dir = i >> 5;
        int c = i & 31;
        int t = threadIdx.x;
        const float wgt = (dir == 0) ? irw[1] : irw[3];
        const u16* x = F + ((size_t)b * 32 + c) * HW;
        u16* o = catt + (size_t)((dir == 0 ? 1 : 3) * 32 + c) * HW;
        // I/O mapping: vec v = k*256+t -> row = v>>3, colgroup = v&7 (4 cols each)
        float r32[2][8][4];  // staged loads (converted), fully static indexing
        float carry = 0.f;
        {
            int wb0 = (dir == 0) ? 0 : 7 * 32;
#pragma unroll
            for (int k = 0; k < 8; ++k) {
                int v = k * 256 + t, row = v >> 3, cg = v & 7;
                ushort4 u = *(const ushort4*)(x + row * WD + wb0 + cg * 4);
                r32[0][k][0] = b2f(u.x); r32[0][k][1] = b2f(u.y);
                r32[0][k][2] = b2f(u.z); r32[0][k][3] = b2f(u.w);
            }
        }
#pragma unroll
        for (int tw = 0; tw < 8; ++tw) {
            int wbase = (dir == 0) ? tw * 32 : (7 - tw) * 32;
            const int cur = tw & 1, nxt = cur ^ 1;
            __syncthreads();
#pragma unroll
            for (int k = 0; k < 8; ++k) {
                int v = k * 256 + t, row = v >> 3, cg = v & 7;
#pragma unroll
                for (int q = 0; q < 4; ++q)
                    stile[row * 33 + cg * 4 + q] = r32[cur][k][q];
            }
            __syncthreads();
            if (tw < 7) {
                int wb2 = (dir == 0) ? (tw + 1) * 32 : (6 - tw) * 32;
#pragma unroll
                for (int k = 0; k < 8; ++k) {
                    int v = k * 256 + t, row = v >> 3, cg = v & 7;
                    ushort4 u = *(const ushort4*)(x + row * WD + wb2 + cg * 4);
                    r32[nxt][k][0] = b2f(u.x); r32[nxt][k][1] = b2f(u.y);
                    r32[nxt][k][2] = b2f(u.z); r32[nxt][k][3] = b2f(u.w);
                }
            }
            if (dir == 0) {
#pragma unroll
                for (int j = 0; j < 32; ++j) {
                    float xv = stile[t * 33 + j];
                    carry = (wbase + j == 0) ? xv : frelu(fmaf(carry, wgt, xv));
                    stile[t * 33 + j] = carry;
                }
            } else {
#pragma unroll
                for (int j = 31; j >= 0; --j) {
                    float xv = stile[t * 33 + j];
                    carry = (wbase + j == WD - 1) ? xv : frelu(fmaf(carry, wgt, xv));
                    stile[t * 33 + j] = carry;
                }
            }
            __syncthreads();
#pragma unroll
            for (int k = 0; k < 8; ++k) {
                int v = k * 256 + t, row = v >> 3, cg = v & 7;
                *(ushort4*)(o + row * WD + wbase + cg * 4) =
                    pack4(stile[row * 33 + cg * 4 + 0], stile[row * 33 + cg * 4 + 1],
                          stile[row * 33 + cg * 4 + 2], stile[row * 33 + cg * 4 + 3]);
            }
        }
    }
}

// ---------------- MFMA conv: OUT[32][HW] = W[32][224] x CAT (linear) ----------------
// block 256 thr = 4 waves; wave owns 2 px-tiles (32 px); 7 K-slabs of 32.
// B-fragments gathered from linear CAT (8 x u16/slab-tile/lane, 4x32B segs/instr),
// ping-pong double buffer, fully static indexing.
// MODE 0: +bias -> F bf16 ; MODE 2: +bias, relu, dot(wo) -> fp32 out
template<int MODE>
__global__ __launch_bounds__(256) void conv_mfma(const u16* __restrict__ CAT,  // [kk][224][HW]
                                                 const u16* __restrict__ WP,   // [7][2][64][8]
                                                 const float* __restrict__ bias,
                                                 const float* __restrict__ wo,
                                                 u16* __restrict__ Fout,
                                                 float* __restrict__ out) {
    int t = threadIdx.x & 63;
    int w = threadIdx.x >> 6;
    int b = blockIdx.y;
    int tile0 = blockIdx.x * 8 + w * 2;
    // lane's B base: channel (t>>4)*8, col px = tile0*16 + (t&15)
    const u16* q0 = CAT + (size_t)b * 224 * HW + (size_t)((t >> 4) * 8) * HW
                  + (size_t)tile0 * 16 + (t & 15);
    const u16* q1 = q0 + 16;

    // A-fragment preload (14 x 16B, L2-hot)
    const short8* ap = (const short8*)WP;
    short8 A[7][2];
#pragma unroll
    for (int s = 0; s < 7; ++s) {
        A[s][0] = ap[(s * 2 + 0) * 64 + t];
        A[s][1] = ap[(s * 2 + 1) * 64 + t];
    }

    f32x4 acc[2][2];
#pragma unroll
    for (int tl = 0; tl < 2; ++tl)
#pragma unroll
        for (int m = 0; m < 2; ++m) acc[tl][m] = (f32x4){0.f, 0.f, 0.f, 0.f};

    u16 rb[2][2][8];   // [phase][tile][j] — compile-time indices after unroll
#pragma unroll
    for (int j = 0; j < 8; ++j) {
        rb[0][0][j] = q0[(size_t)j * HW];
        rb[0][1][j] = q1[(size_t)j * HW];
    }
#pragma unroll
    for (int s = 0; s < 7; ++s) {
        const int cur = s & 1, nxt = cur ^ 1;
        if (s < 6) {
#pragma unroll
            for (int j = 0; j < 8; ++j) {
                rb[nxt][0][j] = q0[(size_t)((s + 1) * 32 + j) * HW];
                rb[nxt][1][j] = q1[(size_t)((s + 1) * 32 + j) * HW];
            }
        }
        short8 B0, B1;
#pragma unroll
        for (int j = 0; j < 8; ++j) {
            B0[j] = (short)rb[cur][0][j];
            B1[j] = (short)rb[cur][1][j];
        }
        acc[0][0] = __builtin_amdgcn_mfma_f32_16x16x32_bf16(A[s][0], B0, acc[0][0], 0, 0, 0);
        acc[0][1] = __builtin_amdgcn_mfma_f32_16x16x32_bf16(A[s][1], B0, acc[0][1], 0, 0, 0);
        acc[1][0] = __builtin_amdgcn_mfma_f32_16x16x32_bf16(A[s][0], B1, acc[1][0], 0, 0, 0);
        acc[1][1] = __builtin_amdgcn_mfma_f32_16x16x32_bf16(A[s][1], B1, acc[1][1], 0, 0, 0);
    }

    // C/D: lane t holds col px=(t&15), rows ch=(t>>4)*4+r (+16*m)
    if (MODE == 0) {
        u16* fb = Fout + (size_t)b * 32 * HW;
#pragma unroll
        for (int tl = 0; tl < 2; ++tl) {
            int px = (tile0 + tl) * 16 + (t & 15);
#pragma unroll
            for (int m = 0; m < 2; ++m)
#pragma unroll
                for (int r = 0; r < 4; ++r) {
                    int ch = m * 16 + (t >> 4) * 4 + r;
                    fb[(size_t)ch * HW + px] = f2b(acc[tl][m][r] + bias[ch]);
                }
        }
    } else {
        float mres0 = 0.f, mres1 = 0.f;
#pragma unroll
        for (int m = 0; m < 2; ++m)
#pragma unroll
            for (int r = 0; r < 4; ++r) {
                int ch = m * 16 + (t >> 4) * 4 + r;
                float wv = wo[ch], bv = bias[ch];
                mres0 = fmaf(wv, frelu(acc[0][m][r] + bv), mres0);
                mres1 = fmaf(wv, frelu(acc[1][m][r] + bv), mres1);
            }
        mres0 += __shfl_xor(mres0, 16); mres0 += __shfl_xor(mres0, 32);
        mres1 += __shfl_xor(mres1, 16); mres1 += __shfl_xor(mres1, 32);
        if (t < 16) {
            out[(size_t)b * HW + (tile0 + 0) * 16 + t] = mres0;
            out[(size_t)b * HW + (tile0 + 1) * 16 + t] = mres1;
        }
    }
}

extern "C" void kernel_launch(void* const* d_in, const int* in_sizes, int n_in,
                              void* d_out, int out_size, void* d_ws, size_t ws_size,
                              hipStream_t stream) {
    const float* x    = (const float*)d_in[0];
    const float* w1   = (const float*)d_in[1];
    const float* b1   = (const float*)d_in[2];
    const float* w2   = (const float*)d_in[3];
    const float* b2   = (const float*)d_in[4];
    const float* w3   = (const float*)d_in[5];
    const float* b3   = (const float*)d_in[6];
    const float* wout = (const float*)d_in[7];
    const float* ir1  = (const float*)d_in[8];
    const float* ir2  = (const float*)d_in[9];

    const size_t fb   = (size_t)32 * HW * 2;        // F bf16: 4 MB/img
    const size_t cb   = (size_t)224 * HW * 2;       // CAT bf16: 29.36 MB/img
    const size_t wext = 64 * 32 * 4 + 2 * 7168 * 2;

    int K = 4;
    while (K > 1 && (size_t)K * (fb + cb) + wext > ws_size) K--;

    char* ws = (char*)d_ws;
    u16*   F    = (u16*)ws;   ws += (size_t)K * fb;
    u16*   CAT  = (u16*)ws;   ws += (size_t)K * cb;
    float* WT1  = (float*)ws; ws += 64 * 32 * 4;
    u16*   WP2  = (u16*)ws;   ws += 7168 * 2;
    u16*   WP3  = (u16*)ws;

    prep_weights<<<1, 256, 0, stream>>>(w1, w2, w3, WT1, WP2, WP3);

    for (int b0 = 0; b0 < 4; b0 += K) {
        int kk = (4 - b0 < K) ? (4 - b0) : K;
        conv1_k<<<dim3(HW / 256, kk), 256, 0, stream>>>(
            x + (size_t)b0 * 64 * HW, WT1, b1, F);
        scan_all<<<dim3(80, kk), 256, 0, stream>>>(F, CAT, ir1);
        conv_mfma<0><<<dim3(HW / 128, kk), 256, 0, stream>>>(
            CAT, WP2, b2, nullptr, F, nullptr);
        scan_all<<<dim3(80, kk), 256, 0, stream>>>(F, CAT, ir2);
        conv_mfma<2><<<dim3(HW / 128, kk), 256, 0, stream>>>(
            CAT, WP3, b3, wout, nullptr, (float*)d_out + (size_t)b0 * HW);
    }
}

// Round 8
// 162.099 us; speedup vs baseline: 4.2536x; 1.1504x over previous
//
#include <hip/hip_runtime.h>
#include <hip/hip_bf16.h>

#define HW 65536
#define WD 256
#define HD 256

typedef unsigned short u16;
typedef __attribute__((ext_vector_type(8))) short short8;
typedef __attribute__((ext_vector_type(4))) float f32x4;

__device__ __forceinline__ float frelu(float v){ return v > 0.f ? v : 0.f; }
__device__ __forceinline__ float b2f(u16 u){ unsigned v = (unsigned)u << 16; float f; __builtin_memcpy(&f, &v, 4); return f; }
__device__ __forceinline__ u16 f2b(float f){ __hip_bfloat16 h = __float2bfloat16(f); u16 u; __builtin_memcpy(&u, &h, 2); return u; }
__device__ __forceinline__ ushort4 pack4(float a, float b, float c, float d){
    ushort4 r; r.x = f2b(a); r.y = f2b(b); r.z = f2b(c); r.w = f2b(d); return r;
}

// CAT layout: LINEAR [224][HW] bf16 per image. folded channel blocks (x32 ch):
// 0=up 1=right 2=down 3=left 4=diagDR(zuoxia+zuoshang) 5=diagDL 6=diagUR
// ---------------- weight prep ----------------
__global__ void prep_weights(const float* __restrict__ w1,
                             const float* __restrict__ w2,
                             const float* __restrict__ w3,
                             float* __restrict__ wt1,   // [64][32] fp32
                             u16* __restrict__ wp2,     // [7][2][64][8] bf16 A-frags
                             u16* __restrict__ wp3) {
    int t = threadIdx.x;
    for (int idx = t; idx < 64 * 32; idx += 256) {
        int i = idx >> 5, o = idx & 31;
        wt1[idx] = w1[o * 64 + i];
    }
    // A-frag pack: lane l holds W[row=l&15 (+16*m)][k=s*32+(l>>4)*8+j]
    for (int idx = t; idx < 7 * 2 * 64 * 8; idx += 256) {
        int j = idx & 7, l = (idx >> 3) & 63, m = (idx >> 9) & 1, s = idx >> 10;
        int o = m * 16 + (l & 15);
        int k = s * 32 + ((l >> 4) * 8) + j;   // folded channel in [0,224)
        int blk = k >> 5, i = k & 31, base = o * 256;
        float v2, v3;
        if (blk < 4)        { v2 = w2[base + blk*32 + i];                   v3 = w3[base + blk*32 + i]; }
        else if (blk == 4)  { v2 = w2[base + 128 + i] + w2[base + 192 + i]; v3 = w3[base + 128 + i] + w3[base + 192 + i]; }
        else if (blk == 5)  { v2 = w2[base + 160 + i];                      v3 = w3[base + 160 + i]; }
        else                { v2 = w2[base + 224 + i];                      v3 = w3[base + 224 + i]; }
        wp2[idx] = f2b(v2);
        wp3[idx] = f2b(v3);
    }
}

// ---------------- conv1: 64ch fp32 -> 32ch bf16, vector FMA ----------------
__global__ __launch_bounds__(256) void conv1_k(const float* __restrict__ in,   // [kk][64][HW]
                                               const float* __restrict__ wt,   // [64][32]
                                               const float* __restrict__ bias,
                                               u16* __restrict__ out) {        // [kk][32][HW]
    int p = blockIdx.x * 256 + threadIdx.x;
    int b = blockIdx.y;
    const float* ip = in + (size_t)b * 64 * HW + p;
    float acc[32];
#pragma unroll
    for (int o = 0; o < 32; ++o) acc[o] = bias[o];
    constexpr int PF = 16;
    float rbuf[PF];
#pragma unroll
    for (int j = 0; j < PF; ++j) rbuf[j] = ip[(size_t)j * HW];
#pragma unroll 1
    for (int i0 = 0; i0 < 64 - PF; i0 += PF) {
        const float* ipn = ip + (size_t)(i0 + PF) * HW;
        const float* wr0 = wt + i0 * 32;
#pragma unroll
        for (int j = 0; j < PF; ++j) {
            float v = rbuf[j];
            rbuf[j] = ipn[(size_t)j * HW];
#pragma unroll
            for (int o = 0; o < 32; ++o) acc[o] = fmaf(wr0[j * 32 + o], v, acc[o]);
        }
    }
    const float* wrL = wt + (64 - PF) * 32;
#pragma unroll
    for (int j = 0; j < PF; ++j) {
        float v = rbuf[j];
#pragma unroll
        for (int o = 0; o < 32; ++o) acc[o] = fmaf(wrL[j * 32 + o], v, acc[o]);
    }
    u16* op = out + (size_t)b * 32 * HW + p;
#pragma unroll
    for (int o = 0; o < 32; ++o) op[(size_t)o * HW] = f2b(acc[o]);
}

// ---------------- row scan, one direction per wave ----------------
// DIR: 0=down 1=diagDR 2=diagDL 3=up 4=diagUR
template<int DIR>
__device__ __forceinline__ void row_scan_dir(const ushort4* __restrict__ xr,
                                             ushort4* __restrict__ ob,
                                             float wgt, int t) {
    constexpr bool FWD = (DIR <= 2);
    constexpr int D = 8;
    ushort4 buf[D];
    const int h0 = FWD ? 0 : HD - 1;
    ushort4 xu = xr[h0 * 64 + t];
    ob[h0 * 64 + t] = xu;
    float s0 = b2f(xu.x), s1 = b2f(xu.y), s2 = b2f(xu.z), s3 = b2f(xu.w);
#pragma unroll
    for (int j = 0; j < D; ++j) {
        int i = 1 + j;
        buf[j] = xr[(FWD ? i : HD - 1 - i) * 64 + t];
    }
    for (int hb = 1; hb < HD; hb += D) {
#pragma unroll
        for (int j = 0; j < D; ++j) {
            int i = hb + j;
            if (i < HD) {
                ushort4 xv = buf[j];
                int in_ = i + D; if (in_ > HD - 1) in_ = HD - 1;
                int h  = FWD ? i : HD - 1 - i;
                int hn = FWD ? in_ : HD - 1 - in_;
                buf[j] = xr[hn * 64 + t];
                float v0 = b2f(xv.x), v1 = b2f(xv.y), v2 = b2f(xv.z), v3 = b2f(xv.w);
                if (DIR == 0 || DIR == 3) {          // axial
                    s0 = frelu(fmaf(s0, wgt, v0));
                    s1 = frelu(fmaf(s1, wgt, v1));
                    s2 = frelu(fmaf(s2, wgt, v2));
                    s3 = frelu(fmaf(s3, wgt, v3));
                } else if (DIR == 1 || DIR == 4) {   // from left neighbor
                    float nb = __shfl_up(s3, 1);
                    float a0 = (t == 0) ? v0 : frelu(fmaf(nb, wgt, v0));
                    float a1 = frelu(fmaf(s0, wgt, v1));
                    float a2 = frelu(fmaf(s1, wgt, v2));
                    float a3 = frelu(fmaf(s2, wgt, v3));
                    s0 = a0; s1 = a1; s2 = a2; s3 = a3;
                } else {                             // DIR==2, from right neighbor
                    float nb = __shfl_down(s0, 1);
                    float a0 = frelu(fmaf(s1, wgt, v0));
                    float a1 = frelu(fmaf(s2, wgt, v1));
                    float a2 = frelu(fmaf(s3, wgt, v2));
                    float a3 = (t == 63) ? v3 : frelu(fmaf(nb, wgt, v3));
                    s0 = a0; s1 = a1; s2 = a2; s3 = a3;
                }
                ob[h * 64 + t] = pack4(s0, s1, s2, s3);
            }
        }
    }
}

// ---------------- merged scans: F bf16 -> CAT bf16 (linear) ----------------
// grid (104, kk), 256 thr.
//  bx 0..39 : row scans, wave task = bx*4+wave in [0,160): c=task/5, d=task%5
//  bx 40..103: col scans, (bx-40)>>5 = dir (0 right,1 left), (bx-40)&31 = channel
__global__ __launch_bounds__(256) void scan_all(const u16* __restrict__ F,    // [kk][32][HW]
                                                u16* __restrict__ CAT,        // [kk][224][HW]
                                                const float* __restrict__ irw) {
    int b = blockIdx.y;
    int bx = blockIdx.x;
    __shared__ float stile[256 * 33];
    const float wd = irw[2];
    u16* catt = CAT + (size_t)b * 224 * HW;

    if (bx < 40) {
        int wave = threadIdx.x >> 6;
        int t = threadIdx.x & 63;
        int task = bx * 4 + wave;          // 0..159
        int c = task / 5, d = task % 5;    // d: 0=down 1=diagDR 2=diagDL 3=up 4=diagUR
        const ushort4* xr = (const ushort4*)(F + ((size_t)b * 32 + c) * HW);
        // CAT block per d: down->2, diagDR->4, diagDL->5, up->0, diagUR->6
        const int blkmap[5] = {2, 4, 5, 0, 6};
        ushort4* ob = (ushort4*)(catt + (size_t)(blkmap[d] * 32 + c) * HW);
        float wgt = (d == 3) ? irw[0] : wd;   // only 'up' uses wu; diagonals use wd (source bug)
        switch (d) {
            case 0: row_scan_dir<0>(xr, ob, wgt, t); break;
            case 1: row_scan_dir<1>(xr, ob, wgt, t); break;
            case 2: row_scan_dir<2>(xr, ob, wgt, t); break;
            case 3: row_scan_dir<3>(xr, ob, wgt, t); break;
            default: row_scan_dir<4>(xr, ob, wgt, t); break;
        }
    } else {
        // col scans: right(1)/left(3), LDS-tiled, double-buffered, ushort4 I/O
        int i = bx - 40;
        int dir = i >> 5;
        int c = i & 31;
        int t = threadIdx.x;
        const float wgt = (dir == 0) ? irw[1] : irw[3];
        const u16* x = F + ((size_t)b * 32 + c) * HW;
        u16* o = catt + (size_t)((dir == 0 ? 1 : 3) * 32 + c) * HW;
        // I/O mapping: vec v = k*256+t -> row = v>>3, colgroup = v&7 (4 cols each)
        float r32[2][8][4];  // staged loads (converted), fully static indexing
        float carry = 0.f;
        {
            int wb0 = (dir == 0) ? 0 : 7 * 32;
#pragma unroll
            for (int k = 0; k < 8; ++k) {
                int v = k * 256 + t, row = v >> 3, cg = v & 7;
                ushort4 u = *(const ushort4*)(x + row * WD + wb0 + cg * 4);
                r32[0][k][0] = b2f(u.x); r32[0][k][1] = b2f(u.y);
                r32[0][k][2] = b2f(u.z); r32[0][k][3] = b2f(u.w);
            }
        }
#pragma unroll
        for (int tw = 0; tw < 8; ++tw) {
            int wbase = (dir == 0) ? tw * 32 : (7 - tw) * 32;
            const int cur = tw & 1, nxt = cur ^ 1;
            __syncthreads();
#pragma unroll
            for (int k = 0; k < 8; ++k) {
                int v = k * 256 + t, row = v >> 3, cg = v & 7;
#pragma unroll
                for (int q = 0; q < 4; ++q)
                    stile[row * 33 + cg * 4 + q] = r32[cur][k][q];
            }
            __syncthreads();
            if (tw < 7) {
                int wb2 = (dir == 0) ? (tw + 1) * 32 : (6 - tw) * 32;
#pragma unroll
                for (int k = 0; k < 8; ++k) {
                    int v = k * 256 + t, row = v >> 3, cg = v & 7;
                    ushort4 u = *(const ushort4*)(x + row * WD + wb2 + cg * 4);
                    r32[nxt][k][0] = b2f(u.x); r32[nxt][k][1] = b2f(u.y);
                    r32[nxt][k][2] = b2f(u.z); r32[nxt][k][3] = b2f(u.w);
                }
            }
            if (dir == 0) {
#pragma unroll
                for (int j = 0; j < 32; ++j) {
                    float xv = stile[t * 33 + j];
                    carry = (wbase + j == 0) ? xv : frelu(fmaf(carry, wgt, xv));
                    stile[t * 33 + j] = carry;
                }
            } else {
#pragma unroll
                for (int j = 31; j >= 0; --j) {
                    float xv = stile[t * 33 + j];
                    carry = (wbase + j == WD - 1) ? xv : frelu(fmaf(carry, wgt, xv));
                    stile[t * 33 + j] = carry;
                }
            }
            __syncthreads();
#pragma unroll
            for (int k = 0; k < 8; ++k) {
                int v = k * 256 + t, row = v >> 3, cg = v & 7;
                *(ushort4*)(o + row * WD + wbase + cg * 4) =
                    pack4(stile[row * 33 + cg * 4 + 0], stile[row * 33 + cg * 4 + 1],
                          stile[row * 33 + cg * 4 + 2], stile[row * 33 + cg * 4 + 3]);
            }
        }
    }
}

// ---------------- MFMA conv: OUT[32][HW] = W[32][224] x CAT (linear) ----------------
// block 256 thr = 4 waves; wave owns 2 px-tiles (32 px); 7 K-slabs of 32.
// B-fragments gathered from linear CAT (8 x u16/slab-tile/lane, 4x32B segs/instr),
// ping-pong double buffer, fully static indexing.
// MODE 0: +bias -> F bf16 ; MODE 2: +bias, relu, dot(wo) -> fp32 out
template<int MODE>
__global__ __launch_bounds__(256) void conv_mfma(const u16* __restrict__ CAT,  // [kk][224][HW]
                                                 const u16* __restrict__ WP,   // [7][2][64][8]
                                                 const float* __restrict__ bias,
                                                 const float* __restrict__ wo,
                                                 u16* __restrict__ Fout,
                                                 float* __restrict__ out) {
    int t = threadIdx.x & 63;
    int w = threadIdx.x >> 6;
    int b = blockIdx.y;
    int tile0 = blockIdx.x * 8 + w * 2;
    // lane's B base: channel (t>>4)*8, col px = tile0*16 + (t&15)
    const u16* q0 = CAT + (size_t)b * 224 * HW + (size_t)((t >> 4) * 8) * HW
                  + (size_t)tile0 * 16 + (t & 15);
    const u16* q1 = q0 + 16;

    // A-fragment preload (14 x 16B, L2-hot)
    const short8* ap = (const short8*)WP;
    short8 A[7][2];
#pragma unroll
    for (int s = 0; s < 7; ++s) {
        A[s][0] = ap[(s * 2 + 0) * 64 + t];
        A[s][1] = ap[(s * 2 + 1) * 64 + t];
    }

    f32x4 acc[2][2];
#pragma unroll
    for (int tl = 0; tl < 2; ++tl)
#pragma unroll
        for (int m = 0; m < 2; ++m) acc[tl][m] = (f32x4){0.f, 0.f, 0.f, 0.f};

    u16 rb[2][2][8];   // [phase][tile][j] — compile-time indices after unroll
#pragma unroll
    for (int j = 0; j < 8; ++j) {
        rb[0][0][j] = q0[(size_t)j * HW];
        rb[0][1][j] = q1[(size_t)j * HW];
    }
#pragma unroll
    for (int s = 0; s < 7; ++s) {
        const int cur = s & 1, nxt = cur ^ 1;
        if (s < 6) {
#pragma unroll
            for (int j = 0; j < 8; ++j) {
                rb[nxt][0][j] = q0[(size_t)((s + 1) * 32 + j) * HW];
                rb[nxt][1][j] = q1[(size_t)((s + 1) * 32 + j) * HW];
            }
        }
        short8 B0, B1;
#pragma unroll
        for (int j = 0; j < 8; ++j) {
            B0[j] = (short)rb[cur][0][j];
            B1[j] = (short)rb[cur][1][j];
        }
        acc[0][0] = __builtin_amdgcn_mfma_f32_16x16x32_bf16(A[s][0], B0, acc[0][0], 0, 0, 0);
        acc[0][1] = __builtin_amdgcn_mfma_f32_16x16x32_bf16(A[s][1], B0, acc[0][1], 0, 0, 0);
        acc[1][0] = __builtin_amdgcn_mfma_f32_16x16x32_bf16(A[s][0], B1, acc[1][0], 0, 0, 0);
        acc[1][1] = __builtin_amdgcn_mfma_f32_16x16x32_bf16(A[s][1], B1, acc[1][1], 0, 0, 0);
    }

    // C/D: lane t holds col px=(t&15), rows ch=(t>>4)*4+r (+16*m)
    if (MODE == 0) {
        u16* fb = Fout + (size_t)b * 32 * HW;
#pragma unroll
        for (int tl = 0; tl < 2; ++tl) {
            int px = (tile0 + tl) * 16 + (t & 15);
#pragma unroll
            for (int m = 0; m < 2; ++m)
#pragma unroll
                for (int r = 0; r < 4; ++r) {
                    int ch = m * 16 + (t >> 4) * 4 + r;
                    fb[(size_t)ch * HW + px] = f2b(acc[tl][m][r] + bias[ch]);
                }
        }
    } else {
        float mres0 = 0.f, mres1 = 0.f;
#pragma unroll
        for (int m = 0; m < 2; ++m)
#pragma unroll
            for (int r = 0; r < 4; ++r) {
                int ch = m * 16 + (t >> 4) * 4 + r;
                float wv = wo[ch], bv = bias[ch];
                mres0 = fmaf(wv, frelu(acc[0][m][r] + bv), mres0);
                mres1 = fmaf(wv, frelu(acc[1][m][r] + bv), mres1);
            }
        mres0 += __shfl_xor(mres0, 16); mres0 += __shfl_xor(mres0, 32);
        mres1 += __shfl_xor(mres1, 16); mres1 += __shfl_xor(mres1, 32);
        if (t < 16) {
            out[(size_t)b * HW + (tile0 + 0) * 16 + t] = mres0;
            out[(size_t)b * HW + (tile0 + 1) * 16 + t] = mres1;
        }
    }
}

extern "C" void kernel_launch(void* const* d_in, const int* in_sizes, int n_in,
                              void* d_out, int out_size, void* d_ws, size_t ws_size,
                              hipStream_t stream) {
    const float* x    = (const float*)d_in[0];
    const float* w1   = (const float*)d_in[1];
    const float* b1   = (const float*)d_in[2];
    const float* w2   = (const float*)d_in[3];
    const float* b2   = (const float*)d_in[4];
    const float* w3   = (const float*)d_in[5];
    const float* b3   = (const float*)d_in[6];
    const float* wout = (const float*)d_in[7];
    const float* ir1  = (const float*)d_in[8];
    const float* ir2  = (const float*)d_in[9];

    const size_t fb   = (size_t)32 * HW * 2;        // F bf16: 4 MB/img
    const size_t cb   = (size_t)224 * HW * 2;       // CAT bf16: 29.36 MB/img
    const size_t wext = 64 * 32 * 4 + 2 * 7168 * 2;

    int K = 4;
    while (K > 1 && (size_t)K * (fb + cb) + wext > ws_size) K--;

    char* ws = (char*)d_ws;
    u16*   F    = (u16*)ws;   ws += (size_t)K * fb;
    u16*   CAT  = (u16*)ws;   ws += (size_t)K * cb;
    float* WT1  = (float*)ws; ws += 64 * 32 * 4;
    u16*   WP2  = (u16*)ws;   ws += 7168 * 2;
    u16*   WP3  = (u16*)ws;

    prep_weights<<<1, 256, 0, stream>>>(w1, w2, w3, WT1, WP2, WP3);

    for (int b0 = 0; b0 < 4; b0 += K) {
        int kk = (4 - b0 < K) ? (4 - b0) : K;
        conv1_k<<<dim3(HW / 256, kk), 256, 0, stream>>>(
            x + (size_t)b0 * 64 * HW, WT1, b1, F);
        scan_all<<<dim3(104, kk), 256, 0, stream>>>(F, CAT, ir1);
        conv_mfma<0><<<dim3(HW / 128, kk), 256, 0, stream>>>(
            CAT, WP2, b2, nullptr, F, nullptr);
        scan_all<<<dim3(104, kk), 256, 0, stream>>>(F, CAT, ir2);
        conv_mfma<2><<<dim3(HW / 128, kk), 256, 0, stream>>>(
            CAT, WP3, b3, wout, nullptr, (float*)d_out + (size_t)b0 * HW);
    }
}

// Round 9
// 153.704 us; speedup vs baseline: 4.4859x; 1.0546x over previous
//
#include <hip/hip_runtime.h>
#include <hip/hip_bf16.h>

#define HW 65536
#define WD 256
#define HD 256

typedef unsigned short u16;
typedef __attribute__((ext_vector_type(8))) short short8;
typedef __attribute__((ext_vector_type(4))) float f32x4;

__device__ __forceinline__ float frelu(float v){ return v > 0.f ? v : 0.f; }
__device__ __forceinline__ float b2f(u16 u){ unsigned v = (unsigned)u << 16; float f; __builtin_memcpy(&f, &v, 4); return f; }
__device__ __forceinline__ u16 f2b(float f){ __hip_bfloat16 h = __float2bfloat16(f); u16 u; __builtin_memcpy(&u, &h, 2); return u; }
__device__ __forceinline__ ushort4 pack4(float a, float b, float c, float d){
    ushort4 r; r.x = f2b(a); r.y = f2b(b); r.z = f2b(c); r.w = f2b(d); return r;
}

// CAT layout: LINEAR [224][HW] bf16 per image. folded channel blocks (x32 ch):
// 0=up 1=right 2=down 3=left 4=diagDR(zuoxia+zuoshang) 5=diagDL 6=diagUR
// ---------------- weight prep ----------------
__global__ void prep_weights(const float* __restrict__ w1,
                             const float* __restrict__ w2,
                             const float* __restrict__ w3,
                             float* __restrict__ wt1,   // [64][32] fp32
                             u16* __restrict__ wp2,     // [7][2][64][8] bf16 A-frags
                             u16* __restrict__ wp3) {
    int t = threadIdx.x;
    for (int idx = t; idx < 64 * 32; idx += 256) {
        int i = idx >> 5, o = idx & 31;
        wt1[idx] = w1[o * 64 + i];
    }
    // A-frag pack: lane l holds W[row=l&15 (+16*m)][k=s*32+(l>>4)*8+j]
    for (int idx = t; idx < 7 * 2 * 64 * 8; idx += 256) {
        int j = idx & 7, l = (idx >> 3) & 63, m = (idx >> 9) & 1, s = idx >> 10;
        int o = m * 16 + (l & 15);
        int k = s * 32 + ((l >> 4) * 8) + j;   // folded channel in [0,224)
        int blk = k >> 5, i = k & 31, base = o * 256;
        float v2, v3;
        if (blk < 4)        { v2 = w2[base + blk*32 + i];                   v3 = w3[base + blk*32 + i]; }
        else if (blk == 4)  { v2 = w2[base + 128 + i] + w2[base + 192 + i]; v3 = w3[base + 128 + i] + w3[base + 192 + i]; }
        else if (blk == 5)  { v2 = w2[base + 160 + i];                      v3 = w3[base + 160 + i]; }
        else                { v2 = w2[base + 224 + i];                      v3 = w3[base + 224 + i]; }
        wp2[idx] = f2b(v2);
        wp3[idx] = f2b(v3);
    }
}

// ---------------- conv1: 64ch fp32 -> 32ch bf16, vector FMA ----------------
__global__ __launch_bounds__(256) void conv1_k(const float* __restrict__ in,   // [kk][64][HW]
                                               const float* __restrict__ wt,   // [64][32]
                                               const float* __restrict__ bias,
                                               u16* __restrict__ out) {        // [kk][32][HW]
    int p = blockIdx.x * 256 + threadIdx.x;
    int b = blockIdx.y;
    const float* ip = in + (size_t)b * 64 * HW + p;
    float acc[32];
#pragma unroll
    for (int o = 0; o < 32; ++o) acc[o] = bias[o];
    constexpr int PF = 16;
    float rbuf[PF];
#pragma unroll
    for (int j = 0; j < PF; ++j) rbuf[j] = ip[(size_t)j * HW];
#pragma unroll 1
    for (int i0 = 0; i0 < 64 - PF; i0 += PF) {
        const float* ipn = ip + (size_t)(i0 + PF) * HW;
        const float* wr0 = wt + i0 * 32;
#pragma unroll
        for (int j = 0; j < PF; ++j) {
            float v = rbuf[j];
            rbuf[j] = ipn[(size_t)j * HW];
#pragma unroll
            for (int o = 0; o < 32; ++o) acc[o] = fmaf(wr0[j * 32 + o], v, acc[o]);
        }
    }
    const float* wrL = wt + (64 - PF) * 32;
#pragma unroll
    for (int j = 0; j < PF; ++j) {
        float v = rbuf[j];
#pragma unroll
        for (int o = 0; o < 32; ++o) acc[o] = fmaf(wrL[j * 32 + o], v, acc[o]);
    }
    u16* op = out + (size_t)b * 32 * HW + p;
#pragma unroll
    for (int o = 0; o < 32; ++o) op[(size_t)o * HW] = f2b(acc[o]);
}

// ---------------- row scan, one direction per wave ----------------
// DIR: 0=down 1=diagDR 2=diagDL 3=up 4=diagUR
template<int DIR>
__device__ __forceinline__ void row_scan_dir(const ushort4* __restrict__ xr,
                                             ushort4* __restrict__ ob,
                                             float wgt, int t) {
    constexpr bool FWD = (DIR <= 2);
    constexpr int D = 8;
    ushort4 buf[D];
    const int h0 = FWD ? 0 : HD - 1;
    ushort4 xu = xr[h0 * 64 + t];
    ob[h0 * 64 + t] = xu;
    float s0 = b2f(xu.x), s1 = b2f(xu.y), s2 = b2f(xu.z), s3 = b2f(xu.w);
#pragma unroll
    for (int j = 0; j < D; ++j) {
        int i = 1 + j;
        buf[j] = xr[(FWD ? i : HD - 1 - i) * 64 + t];
    }
    for (int hb = 1; hb < HD; hb += D) {
#pragma unroll
        for (int j = 0; j < D; ++j) {
            int i = hb + j;
            if (i < HD) {
                ushort4 xv = buf[j];
                int in_ = i + D; if (in_ > HD - 1) in_ = HD - 1;
                int h  = FWD ? i : HD - 1 - i;
                int hn = FWD ? in_ : HD - 1 - in_;
                buf[j] = xr[hn * 64 + t];
                float v0 = b2f(xv.x), v1 = b2f(xv.y), v2 = b2f(xv.z), v3 = b2f(xv.w);
                if (DIR == 0 || DIR == 3) {          // axial
                    s0 = frelu(fmaf(s0, wgt, v0));
                    s1 = frelu(fmaf(s1, wgt, v1));
                    s2 = frelu(fmaf(s2, wgt, v2));
                    s3 = frelu(fmaf(s3, wgt, v3));
                } else if (DIR == 1 || DIR == 4) {   // from left neighbor
                    float nb = __shfl_up(s3, 1);
                    float a0 = (t == 0) ? v0 : frelu(fmaf(nb, wgt, v0));
                    float a1 = frelu(fmaf(s0, wgt, v1));
                    float a2 = frelu(fmaf(s1, wgt, v2));
                    float a3 = frelu(fmaf(s2, wgt, v3));
                    s0 = a0; s1 = a1; s2 = a2; s3 = a3;
                } else {                             // DIR==2, from right neighbor
                    float nb = __shfl_down(s0, 1);
                    float a0 = frelu(fmaf(s1, wgt, v0));
                    float a1 = frelu(fmaf(s2, wgt, v1));
                    float a2 = frelu(fmaf(s3, wgt, v2));
                    float a3 = (t == 63) ? v3 : frelu(fmaf(nb, wgt, v3));
                    s0 = a0; s1 = a1; s2 = a2; s3 = a3;
                }
                ob[h * 64 + t] = pack4(s0, s1, s2, s3);
            }
        }
    }
}

// ---------------- merged scans: F bf16 -> CAT bf16 (linear) ----------------
// grid (104, kk), 256 thr. XCD-AFFINE mapping: all readers of channel c get
// bx%8 == c>>2 (blocks map to XCDs round-robin %8), so F channel c is
// HBM-fetched once and L2-served to its other 6 reader waves.
//  rows: bx in [0,40): d = bx>>3 (0..4), g = bx&7; wave w -> c = g*4 + w
//  cols: bx-40 = 8*(dir*4 + (c&3)) + g, g = c>>2
__global__ __launch_bounds__(256) void scan_all(const u16* __restrict__ F,    // [kk][32][HW]
                                                u16* __restrict__ CAT,        // [kk][224][HW]
                                                const float* __restrict__ irw) {
    int b = blockIdx.y;
    int bx = blockIdx.x;
    __shared__ float stile[256 * 33];
    const float wd = irw[2];
    u16* catt = CAT + (size_t)b * 224 * HW;

    if (bx < 40) {
        int d = bx >> 3;                   // direction 0..4: 0=down 1=diagDR 2=diagDL 3=up 4=diagUR
        int g = bx & 7;                    // channel group == XCD
        int wave = threadIdx.x >> 6;
        int t = threadIdx.x & 63;
        int c = g * 4 + wave;
        const ushort4* xr = (const ushort4*)(F + ((size_t)b * 32 + c) * HW);
        // CAT block per d: down->2, diagDR->4, diagDL->5, up->0, diagUR->6
        const int blkmap[5] = {2, 4, 5, 0, 6};
        ushort4* ob = (ushort4*)(catt + (size_t)(blkmap[d] * 32 + c) * HW);
        float wgt = (d == 3) ? irw[0] : wd;   // only 'up' uses wu; diagonals use wd (source bug)
        switch (d) {
            case 0: row_scan_dir<0>(xr, ob, wgt, t); break;
            case 1: row_scan_dir<1>(xr, ob, wgt, t); break;
            case 2: row_scan_dir<2>(xr, ob, wgt, t); break;
            case 3: row_scan_dir<3>(xr, ob, wgt, t); break;
            default: row_scan_dir<4>(xr, ob, wgt, t); break;
        }
    } else {
        // col scans: right(1)/left(3), LDS-tiled, double-buffered, ushort4 I/O
        int k = bx - 40;                   // 0..63
        int g = k & 7;
        int q = k >> 3;                    // 0..7 = dir*4 + (c&3)
        int dir = q >> 2;
        int c = g * 4 + (q & 3);
        int t = threadIdx.x;
        const float wgt = (dir == 0) ? irw[1] : irw[3];
        const u16* x = F + ((size_t)b * 32 + c) * HW;
        u16* o = catt + (size_t)((dir == 0 ? 1 : 3) * 32 + c) * HW;
        // I/O mapping: vec v = k*256+t -> row = v>>3, colgroup = v&7 (4 cols each)
        float r32[2][8][4];  // staged loads (converted), fully static indexing
        float carry = 0.f;
        {
            int wb0 = (dir == 0) ? 0 : 7 * 32;
#pragma unroll
            for (int kk2 = 0; kk2 < 8; ++kk2) {
                int v = kk2 * 256 + t, row = v >> 3, cg = v & 7;
                ushort4 u = *(const ushort4*)(x + row * WD + wb0 + cg * 4);
                r32[0][kk2][0] = b2f(u.x); r32[0][kk2][1] = b2f(u.y);
                r32[0][kk2][2] = b2f(u.z); r32[0][kk2][3] = b2f(u.w);
            }
        }
#pragma unroll
        for (int tw = 0; tw < 8; ++tw) {
            int wbase = (dir == 0) ? tw * 32 : (7 - tw) * 32;
            const int cur = tw & 1, nxt = cur ^ 1;
            __syncthreads();
#pragma unroll
            for (int kk2 = 0; kk2 < 8; ++kk2) {
                int v = kk2 * 256 + t, row = v >> 3, cg = v & 7;
#pragma unroll
                for (int qq = 0; qq < 4; ++qq)
                    stile[row * 33 + cg * 4 + qq] = r32[cur][kk2][qq];
            }
            __syncthreads();
            if (tw < 7) {
                int wb2 = (dir == 0) ? (tw + 1) * 32 : (6 - tw) * 32;
#pragma unroll
                for (int kk2 = 0; kk2 < 8; ++kk2) {
                    int v = kk2 * 256 + t, row = v >> 3, cg = v & 7;
                    ushort4 u = *(const ushort4*)(x + row * WD + wb2 + cg * 4);
                    r32[nxt][kk2][0] = b2f(u.x); r32[nxt][kk2][1] = b2f(u.y);
                    r32[nxt][kk2][2] = b2f(u.z); r32[nxt][kk2][3] = b2f(u.w);
                }
            }
            if (dir == 0) {
#pragma unroll
                for (int j = 0; j < 32; ++j) {
                    float xv = stile[t * 33 + j];
                    carry = (wbase + j == 0) ? xv : frelu(fmaf(carry, wgt, xv));
                    stile[t * 33 + j] = carry;
                }
            } else {
#pragma unroll
                for (int j = 31; j >= 0; --j) {
                    float xv = stile[t * 33 + j];
                    carry = (wbase + j == WD - 1) ? xv : frelu(fmaf(carry, wgt, xv));
                    stile[t * 33 + j] = carry;
                }
            }
            __syncthreads();
#pragma unroll
            for (int kk2 = 0; kk2 < 8; ++kk2) {
                int v = kk2 * 256 + t, row = v >> 3, cg = v & 7;
                *(ushort4*)(o + row * WD + wbase + cg * 4) =
                    pack4(stile[row * 33 + cg * 4 + 0], stile[row * 33 + cg * 4 + 1],
                          stile[row * 33 + cg * 4 + 2], stile[row * 33 + cg * 4 + 3]);
            }
        }
    }
}

// ---------------- MFMA conv: OUT[32][HW] = W[32][224] x CAT (linear) ----------------
// block 256 thr = 4 waves; wave owns 2 px-tiles (32 px); 7 K-slabs of 32.
// B-fragments gathered from linear CAT (8 x u16/slab-tile/lane, 4x32B segs/instr),
// ping-pong double buffer, fully static indexing.
// MODE 0: +bias -> F bf16 ; MODE 2: +bias, relu, dot(wo) -> fp32 out
template<int MODE>
__global__ __launch_bounds__(256) void conv_mfma(const u16* __restrict__ CAT,  // [kk][224][HW]
                                                 const u16* __restrict__ WP,   // [7][2][64][8]
                                                 const float* __restrict__ bias,
                                                 const float* __restrict__ wo,
                                                 u16* __restrict__ Fout,
                                                 float* __restrict__ out) {
    int t = threadIdx.x & 63;
    int w = threadIdx.x >> 6;
    int b = blockIdx.y;
    int tile0 = blockIdx.x * 8 + w * 2;
    // lane's B base: channel (t>>4)*8, col px = tile0*16 + (t&15)
    const u16* q0 = CAT + (size_t)b * 224 * HW + (size_t)((t >> 4) * 8) * HW
                  + (size_t)tile0 * 16 + (t & 15);
    const u16* q1 = q0 + 16;

    // A-fragment preload (14 x 16B, L2-hot)
    const short8* ap = (const short8*)WP;
    short8 A[7][2];
#pragma unroll
    for (int s = 0; s < 7; ++s) {
        A[s][0] = ap[(s * 2 + 0) * 64 + t];
        A[s][1] = ap[(s * 2 + 1) * 64 + t];
    }

    f32x4 acc[2][2];
#pragma unroll
    for (int tl = 0; tl < 2; ++tl)
#pragma unroll
        for (int m = 0; m < 2; ++m) acc[tl][m] = (f32x4){0.f, 0.f, 0.f, 0.f};

    u16 rb[2][2][8];   // [phase][tile][j] — compile-time indices after unroll
#pragma unroll
    for (int j = 0; j < 8; ++j) {
        rb[0][0][j] = q0[(size_t)j * HW];
        rb[0][1][j] = q1[(size_t)j * HW];
    }
#pragma unroll
    for (int s = 0; s < 7; ++s) {
        const int cur = s & 1, nxt = cur ^ 1;
        if (s < 6) {
#pragma unroll
            for (int j = 0; j < 8; ++j) {
                rb[nxt][0][j] = q0[(size_t)((s + 1) * 32 + j) * HW];
                rb[nxt][1][j] = q1[(size_t)((s + 1) * 32 + j) * HW];
            }
        }
        short8 B0, B1;
#pragma unroll
        for (int j = 0; j < 8; ++j) {
            B0[j] = (short)rb[cur][0][j];
            B1[j] = (short)rb[cur][1][j];
        }
        acc[0][0] = __builtin_amdgcn_mfma_f32_16x16x32_bf16(A[s][0], B0, acc[0][0], 0, 0, 0);
        acc[0][1] = __builtin_amdgcn_mfma_f32_16x16x32_bf16(A[s][1], B0, acc[0][1], 0, 0, 0);
        acc[1][0] = __builtin_amdgcn_mfma_f32_16x16x32_bf16(A[s][0], B1, acc[1][0], 0, 0, 0);
        acc[1][1] = __builtin_amdgcn_mfma_f32_16x16x32_bf16(A[s][1], B1, acc[1][1], 0, 0, 0);
    }

    // C/D: lane t holds col px=(t&15), rows ch=(t>>4)*4+r (+16*m)
    if (MODE == 0) {
        u16* fb = Fout + (size_t)b * 32 * HW;
#pragma unroll
        for (int tl = 0; tl < 2; ++tl) {
            int px = (tile0 + tl) * 16 + (t & 15);
#pragma unroll
            for (int m = 0; m < 2; ++m)
#pragma unroll
                for (int r = 0; r < 4; ++r) {
                    int ch = m * 16 + (t >> 4) * 4 + r;
                    fb[(size_t)ch * HW + px] = f2b(acc[tl][m][r] + bias[ch]);
                }
        }
    } else {
        float mres0 = 0.f, mres1 = 0.f;
#pragma unroll
        for (int m = 0; m < 2; ++m)
#pragma unroll
            for (int r = 0; r < 4; ++r) {
                int ch = m * 16 + (t >> 4) * 4 + r;
                float wv = wo[ch], bv = bias[ch];
                mres0 = fmaf(wv, frelu(acc[0][m][r] + bv), mres0);
                mres1 = fmaf(wv, frelu(acc[1][m][r] + bv), mres1);
            }
        mres0 += __shfl_xor(mres0, 16); mres0 += __shfl_xor(mres0, 32);
        mres1 += __shfl_xor(mres1, 16); mres1 += __shfl_xor(mres1, 32);
        if (t < 16) {
            out[(size_t)b * HW + (tile0 + 0) * 16 + t] = mres0;
            out[(size_t)b * HW + (tile0 + 1) * 16 + t] = mres1;
        }
    }
}

extern "C" void kernel_launch(void* const* d_in, const int* in_sizes, int n_in,
                              void* d_out, int out_size, void* d_ws, size_t ws_size,
                              hipStream_t stream) {
    const float* x    = (const float*)d_in[0];
    const float* w1   = (const float*)d_in[1];
    const float* b1   = (const float*)d_in[2];
    const float* w2   = (const float*)d_in[3];
    const float* b2   = (const float*)d_in[4];
    const float* w3   = (const float*)d_in[5];
    const float* b3   = (const float*)d_in[6];
    const float* wout = (const float*)d_in[7];
    const float* ir1  = (const float*)d_in[8];
    const float* ir2  = (const float*)d_in[9];

    const size_t fb   = (size_t)32 * HW * 2;        // F bf16: 4 MB/img
    const size_t cb   = (size_t)224 * HW * 2;       // CAT bf16: 29.36 MB/img
    const size_t wext = 64 * 32 * 4 + 2 * 7168 * 2;

    int K = 4;
    while (K > 1 && (size_t)K * (fb + cb) + wext > ws_size) K--;

    char* ws = (char*)d_ws;
    u16*   F    = (u16*)ws;   ws += (size_t)K * fb;
    u16*   CAT  = (u16*)ws;   ws += (size_t)K * cb;
    float* WT1  = (float*)ws; ws += 64 * 32 * 4;
    u16*   WP2  = (u16*)ws;   ws += 7168 * 2;
    u16*   WP3  = (u16*)ws;

    prep_weights<<<1, 256, 0, stream>>>(w1, w2, w3, WT1, WP2, WP3);

    for (int b0 = 0; b0 < 4; b0 += K) {
        int kk = (4 - b0 < K) ? (4 - b0) : K;
        conv1_k<<<dim3(HW / 256, kk), 256, 0, stream>>>(
            x + (size_t)b0 * 64 * HW, WT1, b1, F);
        scan_all<<<dim3(104, kk), 256, 0, stream>>>(F, CAT, ir1);
        conv_mfma<0><<<dim3(HW / 128, kk), 256, 0, stream>>>(
            CAT, WP2, b2, nullptr, F, nullptr);
        scan_all<<<dim3(104, kk), 256, 0, stream>>>(F, CAT, ir2);
        conv_mfma<2><<<dim3(HW / 128, kk), 256, 0, stream>>>(
            CAT, WP3, b3, wout, nullptr, (float*)d_out + (size_t)b0 * HW);
    }
}